// Round 1
// baseline (560.608 us; speedup 1.0000x reference)
//
#include <hip/hip_runtime.h>
#include <hip/hip_cooperative_groups.h>
#include <stdint.h>
#include <math.h>

namespace cg = cooperative_groups;

// OTLoss: ft(4096x1024), fs(4096x1024) fp32 -> (loss, P[4096x4096], M[4096x4096])
//
// Pipeline:
//  1) row-normalize ft, fs -> bf16 A, B (ws)
//  2) M_raw = A @ B^T via mfma_f32_16x16x32_bf16, 128x128 tiles, global_load_lds
//     epilogue: atomic sum/sumsq (mean/std) + per-row max (ordered-uint atomicMax)
//  3) stats: mean, inv_std (ddof=1)
//  4) ONE cooperative kernel (256 blocks x 512 thr, 1 block/CU):
//     - phase0: standardize M in place; K = exp(Mstd - rowmax) kept ENTIRELY IN
//       REGISTERS (each thread owns 16 rows x 8 cols = 16x halfx8 = 32 VGPRs)
//     - 20 Sinkhorn iters: u = r/(Kv) per-block (row strip); t = K^T u via
//       per-block partials -> tg[256][4096] -> deterministic col reduce;
//       maxdev check; v_j = c/t_j recomputed from t on the fly (registers)
//       2 grid.sync() per iter
//     - final: w = 1/(Kv); s = K^T w; P_ij = K_ij*w_i/s_j; loss = ||P-I||_F

#define NN 4096
#define DIM 1024
#define OT_ITERS 20
#define OT_EPS_F 1e-6f
#define RC (1.0f/4096.0f)
#define RPB 16   // K rows per block
#define SBT 512  // sinkhorn block threads (8 cols each)

typedef __bf16 bf16_t;
typedef _Float16 half_t;
typedef __bf16 bf16x8 __attribute__((ext_vector_type(8)));
typedef _Float16 halfx8 __attribute__((ext_vector_type(8)));
typedef float floatx4 __attribute__((ext_vector_type(4)));

typedef __attribute__((address_space(1))) void gv_t;
typedef __attribute__((address_space(3))) void lv_t;

// ordered-uint encoding so uint atomicMax == float max (handles both signs)
__device__ __forceinline__ uint32_t fkey(float x) {
  uint32_t b = __float_as_uint(x);
  return (b & 0x80000000u) ? ~b : (b | 0x80000000u);
}
__device__ __forceinline__ float funkey(uint32_t k) {
  uint32_t b = (k & 0x80000000u) ? (k & 0x7fffffffu) : ~k;
  return __uint_as_float(b);
}

// async global->LDS, 16B per lane; lds dst = wave-uniform base, HW adds lane*16
__device__ __forceinline__ void gld_lds16(const void* g, void* lds_uniform) {
  uint32_t loff = (uint32_t)(uintptr_t)lds_uniform;
  loff = (uint32_t)__builtin_amdgcn_readfirstlane((int)loff);
  __builtin_amdgcn_global_load_lds((gv_t*)(uintptr_t)g, (lv_t*)(uintptr_t)loff, 16, 0, 0);
}

// ---------------- init ----------------
__global__ void init_ws(uint32_t* rowmaxKey, float* scal, uint32_t* mdArr) {
  int i = blockIdx.x * 256 + threadIdx.x;
  if (i < NN) rowmaxKey[i] = 0u;
  if (i < 8) ((uint32_t*)scal)[i] = 0u;  // sum, sumsq, mean, inv_std, lossAcc, ...
  if (i < OT_ITERS) mdArr[i] = 0u;
}

// ---------------- row normalize + bf16 cast ----------------
__global__ __launch_bounds__(256) void norm_rows(const float* __restrict__ X,
                                                 bf16_t* __restrict__ Y) {
  int tid = threadIdx.x;
  int wave = tid >> 6, lane = tid & 63;
  int row = blockIdx.x * 4 + wave;
  const float* xr = X + (size_t)row * DIM;
  float xv[16];
  float ss = 0.f;
#pragma unroll
  for (int k = 0; k < 16; k++) { xv[k] = xr[lane + 64 * k]; ss += xv[k] * xv[k]; }
#pragma unroll
  for (int off = 1; off < 64; off <<= 1) ss += __shfl_xor(ss, off, 64);
  float inv = rsqrtf(ss);  // norm ~ 32 >> 1e-12 floor, floor never binds
  bf16_t* yr = Y + (size_t)row * DIM;
#pragma unroll
  for (int k = 0; k < 16; k++) yr[lane + 64 * k] = (bf16_t)(xv[k] * inv);
}

// ---------------- GEMM: C = A @ B^T (both row-major, K-contiguous) ----------------
__global__ __launch_bounds__(256) void gemm_bt(const bf16_t* __restrict__ A,
                                               const bf16_t* __restrict__ B,
                                               float* __restrict__ C,
                                               float* __restrict__ scal,
                                               uint32_t* __restrict__ rowmaxKey) {
  __shared__ __align__(16) bf16_t As[128 * 32];
  __shared__ __align__(16) bf16_t Bs[128 * 32];
  int tid = threadIdx.x;
  int wave = tid >> 6, lane = tid & 63;
  int quad = lane >> 4, l16 = lane & 15;
  int bm = blockIdx.y, bn = blockIdx.x;
  int waveM = wave >> 1, waveN = wave & 1;  // 2x2 waves, each 64x64
  floatx4 acc[4][4] = {};

  for (int k0 = 0; k0 < DIM; k0 += 32) {
#pragma unroll
    for (int t = 0; t < 2; t++) {
      int cbase = t * 256 + wave * 64;  // wave-uniform chunk base
      int c = cbase + lane;             // chunk: 16B = 8 bf16
      int row = c >> 2, kc = c & 3;     // tile row, k-subchunk
      gld_lds16(A + (size_t)(bm * 128 + row) * DIM + (k0 + kc * 8), (char*)As + (size_t)cbase * 16);
      gld_lds16(B + (size_t)(bn * 128 + row) * DIM + (k0 + kc * 8), (char*)Bs + (size_t)cbase * 16);
    }
    __syncthreads();  // drains vmcnt before barrier
    bf16x8 af[4], bfr[4];
#pragma unroll
    for (int mt = 0; mt < 4; mt++)
      af[mt] = *(const bf16x8*)(As + (waveM * 64 + mt * 16 + l16) * 32 + quad * 8);
#pragma unroll
    for (int nt = 0; nt < 4; nt++)
      bfr[nt] = *(const bf16x8*)(Bs + (waveN * 64 + nt * 16 + l16) * 32 + quad * 8);
#pragma unroll
    for (int mt = 0; mt < 4; mt++)
#pragma unroll
      for (int nt = 0; nt < 4; nt++)
        acc[mt][nt] = __builtin_amdgcn_mfma_f32_16x16x32_bf16(af[mt], bfr[nt], acc[mt][nt], 0, 0, 0);
    __syncthreads();
  }

  // epilogue: write C (fp32), accumulate sum/sumsq, per-row max
  // C/D layout (m89-verified): col = lane&15, row = quad*4 + reg
  float lsum = 0.f, lsq = 0.f;
#pragma unroll
  for (int mt = 0; mt < 4; mt++) {
#pragma unroll
    for (int r = 0; r < 4; r++) {
      int gi = bm * 128 + waveM * 64 + mt * 16 + quad * 4 + r;
      float rmax = -3.4e38f;
#pragma unroll
      for (int nt = 0; nt < 4; nt++) {
        float vv = acc[mt][nt][r];
        int gj = bn * 128 + waveN * 64 + nt * 16 + l16;
        C[(size_t)gi * NN + gj] = vv;
        lsum += vv;
        lsq += vv * vv;
        rmax = fmaxf(rmax, vv);
      }
#pragma unroll
      for (int off = 1; off < 16; off <<= 1) rmax = fmaxf(rmax, __shfl_xor(rmax, off, 64));
      if (l16 == 0) atomicMax(rowmaxKey + gi, fkey(rmax));
    }
  }
#pragma unroll
  for (int off = 1; off < 64; off <<= 1) {
    lsum += __shfl_xor(lsum, off, 64);
    lsq += __shfl_xor(lsq, off, 64);
  }
  if (lane == 0) { atomicAdd(&scal[0], lsum); atomicAdd(&scal[1], lsq); }
}

// ---------------- mean / inv_std ----------------
__global__ void stats_kernel(float* scal) {
  double sum = (double)scal[0], sumsq = (double)scal[1];
  double N = (double)NN * (double)NN;
  double mean = sum / N;
  double var = (sumsq - sum * sum / N) / (N - 1.0);  // ddof=1
  scal[2] = (float)mean;
  scal[3] = (float)(1.0 / sqrt(var));
}

// ---------------- fused cooperative Sinkhorn ----------------
// 256 blocks x 512 threads. Block b owns K rows [16b,16b+16); thread owns cols
// [8*tid, 8*tid+8). K strip lives in registers: kreg[16] (halfx8 each).
__global__ __launch_bounds__(SBT, 1) void sinkhorn_full(
    float* __restrict__ M,            // in: M_raw (GEMM out), out: standardized M
    float* __restrict__ P,            // P output (out+1, NOT 16B aligned -> scalar stores)
    const float* __restrict__ scal,   // [2]=mean [3]=inv_std
    const uint32_t* __restrict__ rowmaxKey,
    float* __restrict__ t,            // [4096] colsum K^T u
    float* __restrict__ s,            // [4096] final colsum
    float* __restrict__ tg,           // [256][4096] per-block partials
    uint32_t* __restrict__ mdArr,     // [20] per-iter maxdev (ordered-uint)
    float* __restrict__ lossAcc) {
  __shared__ float red[8 * RPB];   // 8 waves x 16 row-partials
  __shared__ float u_lds[RPB];
  __shared__ float scratch[SBT];

  cg::grid_group grid = cg::this_grid();
  const int b = blockIdx.x;
  const int tid = threadIdx.x;
  const int wave = tid >> 6, lane = tid & 63;
  const int g0 = b * RPB;
  const int c0 = tid * 8;  // this thread's 8 columns

  // ---- phase 0: standardize M strip in place, build K strip in registers ----
  const float mean = scal[2], istd = scal[3];
  halfx8 kreg[RPB];
#pragma unroll
  for (int i = 0; i < RPB; i++) {
    float rmax = funkey(rowmaxKey[g0 + i]);
    float* mrow = M + (size_t)(g0 + i) * NN;
    halfx8 kp;
#pragma unroll
    for (int q = 0; q < 8; q++) {
      float raw = mrow[c0 + q];
      mrow[c0 + q] = (raw - mean) * istd;
      kp[q] = (half_t)__expf((raw - rmax) * istd);  // exp(Mstd - rowmax(Mstd)), gamma=1
    }
    kreg[i] = kp;
  }

  float vr[8];  // v for this thread's 8 columns (register-resident)
#pragma unroll
  for (int q = 0; q < 8; q++) vr[q] = 1.0f;

  // u_i = scale / sum_j K_ij v_j for block rows; then tg[b][:] = partial K^T u
  auto matvec_phase = [&](float scale) {
    float part[RPB];
#pragma unroll
    for (int i = 0; i < RPB; i++) {
      float p = 0.f;
#pragma unroll
      for (int q = 0; q < 8; q++) p += (float)kreg[i][q] * vr[q];
      part[i] = p;
    }
#pragma unroll
    for (int off = 1; off < 64; off <<= 1)
#pragma unroll
      for (int i = 0; i < RPB; i++) part[i] += __shfl_xor(part[i], off, 64);
    if (lane == 0) {
#pragma unroll
      for (int i = 0; i < RPB; i++) red[wave * RPB + i] = part[i];
    }
    __syncthreads();
    if (tid < RPB) {
      float dsum = 0.f;
#pragma unroll
      for (int w = 0; w < 8; w++) dsum += red[w * RPB + tid];
      u_lds[tid] = scale / dsum;
    }
    __syncthreads();
    float ta[8];
#pragma unroll
    for (int q = 0; q < 8; q++) ta[q] = 0.f;
#pragma unroll
    for (int i = 0; i < RPB; i++) {
      float ui = u_lds[i];
#pragma unroll
      for (int q = 0; q < 8; q++) ta[q] += (float)kreg[i][q] * ui;
    }
    float* tgb = tg + (size_t)b * NN;
#pragma unroll
    for (int q = 0; q < 8; q++) tgb[c0 + q] = ta[q];
  };

  // deterministic fixed-order reduce of tg over 256 blocks for this block's
  // 16 owned columns; result valid for tid < 16
  auto colreduce = [&]() -> float {
    int jl = tid & 15, seg = tid >> 4;  // seg in [0,32), 8 partials each
    int j = g0 + jl;
    float acc = 0.f;
#pragma unroll
    for (int m = 0; m < 8; m++) acc += tg[(size_t)(seg * 8 + m) * NN + j];
    scratch[tid] = acc;
    __syncthreads();
    float tn = 0.f;
    if (tid < RPB) {
#pragma unroll
      for (int k = 0; k < 32; k++) tn += scratch[tid + RPB * k];
    }
    return tn;
  };

  // ---- Sinkhorn loop: u = r/(Kv); t = K^T u; maxdev; v = c/t ----
  bool frozen = false;
  for (int it = 0; it < OT_ITERS; it++) {
    if (it > 0) {
#pragma unroll
      for (int q = 0; q < 8; q++) vr[q] = RC / t[c0 + q];  // v from prev iter's t
    }
    matvec_phase(RC);
    grid.sync();
    float tn = colreduce();
    if (tid < RPB) {
      int j = g0 + tid;
      float vj = (it == 0) ? 1.0f : (RC / t[j]);  // v used THIS iter
      float dev = fabsf(vj * tn - RC);            // beta_j - c
      t[j] = tn;
#pragma unroll
      for (int off = 1; off < RPB; off <<= 1) dev = fmaxf(dev, __shfl_xor(dev, off, 64));
      if (tid == 0) atomicMax(&mdArr[it], fkey(dev));
    }
    grid.sync();
    float md = funkey(((volatile const uint32_t*)mdArr)[it]);
    if (md <= OT_EPS_F) { frozen = true; break; }  // keep row-normalized P1: v unchanged
  }
  if (!frozen) {
#pragma unroll
    for (int q = 0; q < 8; q++) vr[q] = RC / t[c0 + q];  // commit final col-normalize v
  }

  // ---- final: w = 1/(Kv); s = K^T w; P_ij = K_ij * w_i / s_j (v cancels) ----
  matvec_phase(1.0f);  // u_lds now holds w_i
  grid.sync();
  float tn = colreduce();
  if (tid < RPB) s[g0 + tid] = tn;
  grid.sync();

  float isv[8];
#pragma unroll
  for (int q = 0; q < 8; q++) isv[q] = 1.0f / s[c0 + q];
  float ls = 0.f;
#pragma unroll
  for (int i = 0; i < RPB; i++) {
    int gi = g0 + i;
    float wi = u_lds[i];
    float* prow = P + (size_t)gi * NN;  // unaligned base (out+1): scalar stores
#pragma unroll
    for (int q = 0; q < 8; q++) {
      float p = (float)kreg[i][q] * wi * isv[q];
      prow[c0 + q] = p;
      float d = p - ((gi == c0 + q) ? 1.0f : 0.0f);
      ls += d * d;
    }
  }
#pragma unroll
  for (int off = 1; off < 64; off <<= 1) ls += __shfl_xor(ls, off, 64);
  __syncthreads();
  if (lane == 0) red[wave] = ls;
  __syncthreads();
  if (tid == 0) {
    float tot = 0.f;
#pragma unroll
    for (int w = 0; w < 8; w++) tot += red[w];
    atomicAdd(lossAcc, tot);
  }
}

__global__ void final_loss(float* out, const float* lossAcc) { out[0] = sqrtf(*lossAcc); }

// ---------------- launch ----------------
extern "C" void kernel_launch(void* const* d_in, const int* in_sizes, int n_in, void* d_out,
                              int out_size, void* d_ws, size_t ws_size, hipStream_t stream) {
  const float* ft = (const float*)d_in[0];
  const float* fs = (const float*)d_in[1];
  float* out = (float*)d_out;

  char* ws = (char*)d_ws;
  bf16_t* A = (bf16_t*)ws;                  //  8 MiB
  bf16_t* B = (bf16_t*)(ws + (8u << 20));   //  8 MiB
  float* tg = (float*)(ws + (16u << 20));   //  4 MiB: per-block col partials
  float* fbase = (float*)(ws + (24u << 20));
  float* t = fbase;                          // 4096
  float* s = fbase + 4096;                   // 4096
  uint32_t* rowmaxKey = (uint32_t*)(fbase + 8192);
  float* scal = fbase + 12288;               // [0]=sum [1]=sumsq [2]=mean [3]=inv_std [4]=lossAcc
  uint32_t* mdArr = (uint32_t*)(fbase + 12296);  // [20] per-iter maxdev
  float* lossAcc = scal + 4;

  float* P_out = out + 1;
  float* M_out = out + 1 + (size_t)NN * NN;  // scratch for M_raw, then standardized M

  init_ws<<<16, 256, 0, stream>>>(rowmaxKey, scal, mdArr);
  norm_rows<<<1024, 256, 0, stream>>>(ft, A);
  norm_rows<<<1024, 256, 0, stream>>>(fs, B);
  gemm_bt<<<dim3(32, 32), 256, 0, stream>>>(A, B, M_out, scal, rowmaxKey);
  stats_kernel<<<1, 1, 0, stream>>>(scal);

  void* args[] = {&M_out, &P_out, &scal, &rowmaxKey, &t, &s, &tg, &mdArr, &lossAcc};
  hipLaunchCooperativeKernel((void*)sinkhorn_full, dim3(256), dim3(SBT), args, 0, stream);

  final_loss<<<1, 1, 0, stream>>>(out, scal + 4);
}

// Round 2
// 464.569 us; speedup vs baseline: 1.2067x; 1.2067x over previous
//
#include <hip/hip_runtime.h>
#include <stdint.h>
#include <math.h>

// OTLoss: ft(4096x1024), fs(4096x1024) fp32 -> (loss, P[4096x4096], M[4096x4096])
//
// Pipeline:
//  1) row-normalize ft, fs -> bf16 A, B (ws)
//  2) M_raw = A @ B^T via mfma_f32_16x16x32_bf16, 128x128 tiles, global_load_lds
//     epilogue: atomic sum/sumsq (mean/std) + per-row max (ordered-uint atomicMax)
//  3) ONE cooperative-launched persistent kernel (256 blocks x 512 thr, 1/CU):
//     - stats (mean, inv_std ddof=1) computed redundantly per block from scal[0..1]
//     - phase0: standardize M in place (float4); K = exp(Mstd - rowmax) kept
//       ENTIRELY IN REGISTERS (thread owns 16 rows x 8 cols = 16x halfx8 = 64 VGPR)
//     - 20 Sinkhorn iters: u = r/(Kv) block-local; t = K^T u via per-block
//       partials tg[256][4096] -> owner col reduce; per-block maxdev via devArr
//       (no contended atomics); 2 tree-barriers per iter
//     - final: w = 1/(Kv); s = K^T w; P_ij = K_ij*w_i/s_j; loss = ||P-I||_F
//     Grid sync = hand-rolled 2-level tree barrier (8x32 -> root -> gen flag):
//     cg::grid.sync() measured ~4.4us (256 serialized same-line RMWs + coarse
//     sleep backoff); tree arrival is 32-way parallel x 8 lines + relaxed-load spin.

#define NN 4096
#define DIM 1024
#define OT_ITERS 20
#define OT_EPS_F 1e-6f
#define RC (1.0f/4096.0f)
#define RPB 16   // K rows per block
#define SBT 512  // sinkhorn block threads (8 cols each)

typedef __bf16 bf16_t;
typedef _Float16 half_t;
typedef __bf16 bf16x8 __attribute__((ext_vector_type(8)));
typedef _Float16 halfx8 __attribute__((ext_vector_type(8)));
typedef float floatx4 __attribute__((ext_vector_type(4)));

typedef __attribute__((address_space(1))) void gv_t;
typedef __attribute__((address_space(3))) void lv_t;

// ordered-uint encoding so uint atomicMax == float max (handles both signs)
__device__ __forceinline__ uint32_t fkey(float x) {
  uint32_t b = __float_as_uint(x);
  return (b & 0x80000000u) ? ~b : (b | 0x80000000u);
}
__device__ __forceinline__ float funkey(uint32_t k) {
  uint32_t b = (k & 0x80000000u) ? (k & 0x7fffffffu) : ~k;
  return __uint_as_float(b);
}

// async global->LDS, 16B per lane; lds dst = wave-uniform base, HW adds lane*16
__device__ __forceinline__ void gld_lds16(const void* g, void* lds_uniform) {
  uint32_t loff = (uint32_t)(uintptr_t)lds_uniform;
  loff = (uint32_t)__builtin_amdgcn_readfirstlane((int)loff);
  __builtin_amdgcn_global_load_lds((gv_t*)(uintptr_t)g, (lv_t*)(uintptr_t)loff, 16, 0, 0);
}

// ---- 2-level tree grid barrier --------------------------------------------
// bar layout (uint32 words): cnt[grp] at grp*64 (grp<8, separate lines),
// root at 512, gen at 576. All zeroed by init_ws each launch.
// Release on arrival (flushes this XCD's L2), acquire fence on exit
// (invalidates local caches) -- same semantics cg::grid.sync() provided.
__device__ __forceinline__ void gbar(uint32_t* bar, uint32_t g) {
  __syncthreads();  // compiler drains vmcnt before s_barrier -> stores in L2
  if (threadIdx.x == 0) {
    uint32_t* cnt = bar + ((blockIdx.x >> 5) * 64);
    uint32_t* root = bar + 512;
    uint32_t* gen = bar + 576;
    if (__hip_atomic_fetch_add(cnt, 1u, __ATOMIC_RELEASE, __HIP_MEMORY_SCOPE_AGENT) == 31u) {
      __hip_atomic_store(cnt, 0u, __ATOMIC_RELAXED, __HIP_MEMORY_SCOPE_AGENT);
      if (__hip_atomic_fetch_add(root, 1u, __ATOMIC_ACQ_REL, __HIP_MEMORY_SCOPE_AGENT) == 7u) {
        __hip_atomic_store(root, 0u, __ATOMIC_RELAXED, __HIP_MEMORY_SCOPE_AGENT);
        __hip_atomic_store(gen, g, __ATOMIC_RELEASE, __HIP_MEMORY_SCOPE_AGENT);
      }
    }
    while (__hip_atomic_load(gen, __ATOMIC_RELAXED, __HIP_MEMORY_SCOPE_AGENT) < g)
      __builtin_amdgcn_s_sleep(1);
    __builtin_amdgcn_fence(__ATOMIC_ACQUIRE, "agent");
  }
  __syncthreads();
}

// ---------------- init ----------------
__global__ void init_ws(uint32_t* rowmaxKey, float* scal, uint32_t* bar) {
  int i = blockIdx.x * 256 + threadIdx.x;
  if (i < NN) rowmaxKey[i] = 0u;
  if (i < 8) ((uint32_t*)scal)[i] = 0u;  // sum, sumsq, -, -, lossAcc, ...
  if (i < 640) bar[i] = 0u;              // barrier state
}

// ---------------- row normalize + bf16 cast ----------------
__global__ __launch_bounds__(256) void norm_rows(const float* __restrict__ X,
                                                 bf16_t* __restrict__ Y) {
  int tid = threadIdx.x;
  int wave = tid >> 6, lane = tid & 63;
  int row = blockIdx.x * 4 + wave;
  const float* xr = X + (size_t)row * DIM;
  float xv[16];
  float ss = 0.f;
#pragma unroll
  for (int k = 0; k < 16; k++) { xv[k] = xr[lane + 64 * k]; ss += xv[k] * xv[k]; }
#pragma unroll
  for (int off = 1; off < 64; off <<= 1) ss += __shfl_xor(ss, off, 64);
  float inv = rsqrtf(ss);  // norm ~ 32 >> 1e-12 floor, floor never binds
  bf16_t* yr = Y + (size_t)row * DIM;
#pragma unroll
  for (int k = 0; k < 16; k++) yr[lane + 64 * k] = (bf16_t)(xv[k] * inv);
}

// ---------------- GEMM: C = A @ B^T (both row-major, K-contiguous) ----------------
__global__ __launch_bounds__(256) void gemm_bt(const bf16_t* __restrict__ A,
                                               const bf16_t* __restrict__ B,
                                               float* __restrict__ C,
                                               float* __restrict__ scal,
                                               uint32_t* __restrict__ rowmaxKey) {
  __shared__ __align__(16) bf16_t As[128 * 32];
  __shared__ __align__(16) bf16_t Bs[128 * 32];
  int tid = threadIdx.x;
  int wave = tid >> 6, lane = tid & 63;
  int quad = lane >> 4, l16 = lane & 15;
  int bm = blockIdx.y, bn = blockIdx.x;
  int waveM = wave >> 1, waveN = wave & 1;  // 2x2 waves, each 64x64
  floatx4 acc[4][4] = {};

  for (int k0 = 0; k0 < DIM; k0 += 32) {
#pragma unroll
    for (int t = 0; t < 2; t++) {
      int cbase = t * 256 + wave * 64;  // wave-uniform chunk base
      int c = cbase + lane;             // chunk: 16B = 8 bf16
      int row = c >> 2, kc = c & 3;     // tile row, k-subchunk
      gld_lds16(A + (size_t)(bm * 128 + row) * DIM + (k0 + kc * 8), (char*)As + (size_t)cbase * 16);
      gld_lds16(B + (size_t)(bn * 128 + row) * DIM + (k0 + kc * 8), (char*)Bs + (size_t)cbase * 16);
    }
    __syncthreads();  // drains vmcnt before barrier
    bf16x8 af[4], bfr[4];
#pragma unroll
    for (int mt = 0; mt < 4; mt++)
      af[mt] = *(const bf16x8*)(As + (waveM * 64 + mt * 16 + l16) * 32 + quad * 8);
#pragma unroll
    for (int nt = 0; nt < 4; nt++)
      bfr[nt] = *(const bf16x8*)(Bs + (waveN * 64 + nt * 16 + l16) * 32 + quad * 8);
#pragma unroll
    for (int mt = 0; mt < 4; mt++)
#pragma unroll
      for (int nt = 0; nt < 4; nt++)
        acc[mt][nt] = __builtin_amdgcn_mfma_f32_16x16x32_bf16(af[mt], bfr[nt], acc[mt][nt], 0, 0, 0);
    __syncthreads();
  }

  // epilogue: write C (fp32), accumulate sum/sumsq, per-row max
  // C/D layout (m89-verified): col = lane&15, row = quad*4 + reg
  float lsum = 0.f, lsq = 0.f;
#pragma unroll
  for (int mt = 0; mt < 4; mt++) {
#pragma unroll
    for (int r = 0; r < 4; r++) {
      int gi = bm * 128 + waveM * 64 + mt * 16 + quad * 4 + r;
      float rmax = -3.4e38f;
#pragma unroll
      for (int nt = 0; nt < 4; nt++) {
        float vv = acc[mt][nt][r];
        int gj = bn * 128 + waveN * 64 + nt * 16 + l16;
        C[(size_t)gi * NN + gj] = vv;
        lsum += vv;
        lsq += vv * vv;
        rmax = fmaxf(rmax, vv);
      }
#pragma unroll
      for (int off = 1; off < 16; off <<= 1) rmax = fmaxf(rmax, __shfl_xor(rmax, off, 64));
      if (l16 == 0) atomicMax(rowmaxKey + gi, fkey(rmax));
    }
  }
#pragma unroll
  for (int off = 1; off < 64; off <<= 1) {
    lsum += __shfl_xor(lsum, off, 64);
    lsq += __shfl_xor(lsq, off, 64);
  }
  if (lane == 0) { atomicAdd(&scal[0], lsum); atomicAdd(&scal[1], lsq); }
}

// ---------------- fused persistent Sinkhorn ----------------
// 256 blocks x 512 threads (cooperative launch for co-residency guarantee).
// Block b owns K rows [16b,16b+16); thread owns cols [8*tid, 8*tid+8).
__global__ __launch_bounds__(SBT, 1) void sinkhorn_full(
    float* __restrict__ M,            // in: M_raw (GEMM out), out: standardized M
    float* __restrict__ P,            // P output (out+1, NOT 16B aligned -> scalar stores)
    float* __restrict__ scal,         // [0]=sum [1]=sumsq [4]=lossAcc
    const uint32_t* __restrict__ rowmaxKey,
    float* __restrict__ t,            // [4096] colsum K^T u
    float* __restrict__ s,            // [4096] final colsum
    float* __restrict__ tg,           // [256][4096] per-block partials
    float* __restrict__ devArr,       // [256] per-block maxdev
    uint32_t* __restrict__ bar,       // tree-barrier state
    float* __restrict__ out) {        // out[0] = loss
  __shared__ float red[8 * RPB];   // 8 waves x 16 row-partials
  __shared__ float u_lds[RPB];
  __shared__ float scratch[SBT];

  const int b = blockIdx.x;
  const int tid = threadIdx.x;
  const int wave = tid >> 6, lane = tid & 63;
  const int g0 = b * RPB;
  const int c0 = tid * 8;  // this thread's 8 columns
  uint32_t bg = 0;         // barrier generation (identical sequence in every block)

  // ---- stats (redundant per block; gemm atomics visible at kernel boundary) ----
  double sum = (double)scal[0], sumsq = (double)scal[1];
  double Nd = (double)NN * (double)NN;
  double meand = sum / Nd;
  double var = (sumsq - sum * sum / Nd) / (Nd - 1.0);  // ddof=1
  const float mean = (float)meand;
  const float istd = (float)(1.0 / sqrt(var));

  // ---- phase 0: standardize M strip in place (float4), K strip in registers ----
  halfx8 kreg[RPB];
#pragma unroll
  for (int i = 0; i < RPB; i++) {
    float rmax = funkey(rowmaxKey[g0 + i]);
    float* mrow = M + (size_t)(g0 + i) * NN + c0;
    float4 a = *(const float4*)mrow;
    float4 bb = *(const float4*)(mrow + 4);
    float4 sa, sb;
    sa.x = (a.x - mean) * istd;  sa.y = (a.y - mean) * istd;
    sa.z = (a.z - mean) * istd;  sa.w = (a.w - mean) * istd;
    sb.x = (bb.x - mean) * istd; sb.y = (bb.y - mean) * istd;
    sb.z = (bb.z - mean) * istd; sb.w = (bb.w - mean) * istd;
    *(float4*)mrow = sa;
    *(float4*)(mrow + 4) = sb;
    halfx8 kp;
    kp[0] = (half_t)__expf((a.x - rmax) * istd);
    kp[1] = (half_t)__expf((a.y - rmax) * istd);
    kp[2] = (half_t)__expf((a.z - rmax) * istd);
    kp[3] = (half_t)__expf((a.w - rmax) * istd);
    kp[4] = (half_t)__expf((bb.x - rmax) * istd);
    kp[5] = (half_t)__expf((bb.y - rmax) * istd);
    kp[6] = (half_t)__expf((bb.z - rmax) * istd);
    kp[7] = (half_t)__expf((bb.w - rmax) * istd);
    kreg[i] = kp;
  }

  float vr[8];  // v for this thread's 8 columns (register-resident)
#pragma unroll
  for (int q = 0; q < 8; q++) vr[q] = 1.0f;

  // u_i = scale / sum_j K_ij v_j for block rows; then tg[b][:] = partial K^T u
  auto matvec_phase = [&](float scale) {
    float part[RPB];
#pragma unroll
    for (int i = 0; i < RPB; i++) {
      float p = 0.f;
#pragma unroll
      for (int q = 0; q < 8; q++) p += (float)kreg[i][q] * vr[q];
      part[i] = p;
    }
#pragma unroll
    for (int off = 1; off < 64; off <<= 1)
#pragma unroll
      for (int i = 0; i < RPB; i++) part[i] += __shfl_xor(part[i], off, 64);
    if (lane == 0) {
#pragma unroll
      for (int i = 0; i < RPB; i++) red[wave * RPB + i] = part[i];
    }
    __syncthreads();
    if (tid < RPB) {
      float dsum = 0.f;
#pragma unroll
      for (int w = 0; w < 8; w++) dsum += red[w * RPB + tid];
      u_lds[tid] = scale / dsum;
    }
    __syncthreads();
    float ta[8];
#pragma unroll
    for (int q = 0; q < 8; q++) ta[q] = 0.f;
#pragma unroll
    for (int i = 0; i < RPB; i++) {
      float ui = u_lds[i];
#pragma unroll
      for (int q = 0; q < 8; q++) ta[q] += (float)kreg[i][q] * ui;
    }
    float* tgb = tg + (size_t)b * NN;
#pragma unroll
    for (int q = 0; q < 8; q++) tgb[c0 + q] = ta[q];
  };

  // deterministic fixed-order reduce of tg over 256 blocks for this block's
  // 16 owned columns; result valid for tid < 16
  auto colreduce = [&]() -> float {
    int jl = tid & 15, seg = tid >> 4;  // seg in [0,32), 8 partials each
    int j = g0 + jl;
    float acc = 0.f;
#pragma unroll
    for (int m = 0; m < 8; m++) acc += tg[(size_t)(seg * 8 + m) * NN + j];
    scratch[tid] = acc;
    __syncthreads();
    float tn = 0.f;
    if (tid < RPB) {
#pragma unroll
      for (int k = 0; k < 32; k++) tn += scratch[tid + RPB * k];
    }
    return tn;
  };

  // ---- Sinkhorn loop: u = r/(Kv); t = K^T u; maxdev; v = c/t ----
  bool frozen = false;
  for (int it = 0; it < OT_ITERS; it++) {
    if (it > 0) {
      float4 t0 = *(const float4*)(t + c0);
      float4 t1 = *(const float4*)(t + c0 + 4);
      vr[0] = RC / t0.x; vr[1] = RC / t0.y; vr[2] = RC / t0.z; vr[3] = RC / t0.w;
      vr[4] = RC / t1.x; vr[5] = RC / t1.y; vr[6] = RC / t1.z; vr[7] = RC / t1.w;
    }
    matvec_phase(RC);
    gbar(bar, ++bg);
    float tn = colreduce();
    if (tid < RPB) {
      int j = g0 + tid;
      float vj = (it == 0) ? 1.0f : (RC / t[j]);  // v used THIS iter
      float dev = fabsf(vj * tn - RC);            // beta_j - c
      t[j] = tn;
#pragma unroll
      for (int off = 1; off < RPB; off <<= 1) dev = fmaxf(dev, __shfl_xor(dev, off, 64));
      if (tid == 0) devArr[b] = dev;  // per-block store: no contended atomics
    }
    gbar(bar, ++bg);
    // block-local max over 256 per-block devs (max is exact -> deterministic)
    float x = (tid < 256) ? devArr[tid] : 0.f;
#pragma unroll
    for (int off = 1; off < 64; off <<= 1) x = fmaxf(x, __shfl_xor(x, off, 64));
    if (lane == 0 && wave < 4) scratch[300 + wave] = x;
    __syncthreads();
    float md = fmaxf(fmaxf(scratch[300], scratch[301]), fmaxf(scratch[302], scratch[303]));
    if (md <= OT_EPS_F) { frozen = true; break; }  // uniform across blocks
  }
  if (!frozen) {
#pragma unroll
    for (int q = 0; q < 8; q++) vr[q] = RC / t[c0 + q];  // commit final col-normalize v
  }

  // ---- final: w = 1/(Kv); s = K^T w; P_ij = K_ij * w_i / s_j (v cancels) ----
  matvec_phase(1.0f);  // u_lds now holds w_i
  gbar(bar, ++bg);
  float tn = colreduce();
  if (tid < RPB) s[g0 + tid] = tn;
  gbar(bar, ++bg);

  float4 s0 = *(const float4*)(s + c0);
  float4 s1 = *(const float4*)(s + c0 + 4);
  float isv[8] = {1.0f / s0.x, 1.0f / s0.y, 1.0f / s0.z, 1.0f / s0.w,
                  1.0f / s1.x, 1.0f / s1.y, 1.0f / s1.z, 1.0f / s1.w};
  float ls = 0.f;
#pragma unroll
  for (int i = 0; i < RPB; i++) {
    int gi = g0 + i;
    float wi = u_lds[i];
    float* prow = P + (size_t)gi * NN;  // unaligned base (out+1): scalar stores
#pragma unroll
    for (int q = 0; q < 8; q++) {
      float p = (float)kreg[i][q] * wi * isv[q];
      prow[c0 + q] = p;
      float d = p - ((gi == c0 + q) ? 1.0f : 0.0f);
      ls += d * d;
    }
  }
#pragma unroll
  for (int off = 1; off < 64; off <<= 1) ls += __shfl_xor(ls, off, 64);
  __syncthreads();
  if (lane == 0) red[wave] = ls;
  __syncthreads();
  if (tid == 0) {
    float tot = 0.f;
#pragma unroll
    for (int w = 0; w < 8; w++) tot += red[w];
    atomicAdd(&scal[4], tot);
  }
  gbar(bar, ++bg);
  if (b == 0 && tid == 0) out[0] = sqrtf(scal[4]);
}

// ---------------- launch ----------------
extern "C" void kernel_launch(void* const* d_in, const int* in_sizes, int n_in, void* d_out,
                              int out_size, void* d_ws, size_t ws_size, hipStream_t stream) {
  const float* ft = (const float*)d_in[0];
  const float* fs = (const float*)d_in[1];
  float* out = (float*)d_out;

  char* ws = (char*)d_ws;
  bf16_t* A = (bf16_t*)ws;                  //  8 MiB
  bf16_t* B = (bf16_t*)(ws + (8u << 20));   //  8 MiB
  float* tg = (float*)(ws + (16u << 20));   //  4 MiB: per-block col partials
  float* fbase = (float*)(ws + (24u << 20));
  float* t = fbase;                              // 4096
  float* s = fbase + 4096;                       // 4096
  uint32_t* rowmaxKey = (uint32_t*)(fbase + 8192);  // 4096
  float* devArr = fbase + 12288;                 // 256
  float* scal = fbase + 12544;                   // [0]=sum [1]=sumsq [4]=lossAcc
  uint32_t* bar = (uint32_t*)(fbase + 13312);    // 640 words (spaced counters)

  float* P_out = out + 1;
  float* M_out = out + 1 + (size_t)NN * NN;  // scratch for M_raw, then standardized M

  init_ws<<<16, 256, 0, stream>>>(rowmaxKey, scal, bar);
  norm_rows<<<1024, 256, 0, stream>>>(ft, A);
  norm_rows<<<1024, 256, 0, stream>>>(fs, B);
  gemm_bt<<<dim3(32, 32), 256, 0, stream>>>(A, B, M_out, scal, rowmaxKey);

  void* args[] = {&M_out, &P_out, &scal, &rowmaxKey, &t, &s, &tg, &devArr, &bar, &out};
  hipLaunchCooperativeKernel((void*)sinkhorn_full, dim3(256), dim3(SBT), args, 0, stream);
}

// Round 3
// 373.018 us; speedup vs baseline: 1.5029x; 1.2454x over previous
//
#include <hip/hip_runtime.h>
#include <stdint.h>
#include <math.h>

// OTLoss: ft(4096x1024), fs(4096x1024) fp32 -> (loss, P[4096x4096], M[4096x4096])
//
// Pipeline:
//  1) row-normalize ft, fs -> bf16 A, B (ws)
//  2) M_raw = A @ B^T via mfma_f32_16x16x32_bf16, 128x128 tiles, global_load_lds
//     epilogue: per-block partial sum/sumsq -> sumArr/sqArr (plain stores) and
//     per-block per-row max -> rmPart (plain stores). NO contended atomics:
//     the old per-wave atomicAdd on scal[0..1] was 8192 serialized same-line
//     RMWs (~100us tail); rowmax atomicMax was 65K RMWs.
//  3) ONE persistent kernel (PLAIN launch, 256 blocks x 512 thr, 1/CU):
//     grid=256=#CUs and VGPR<=256 guarantee all blocks co-resident, so the
//     hand-rolled tree barrier is safe without hipLaunchCooperativeKernel
//     (coop launch measured ~127us overhead under graph replay, r1/r2).
//     - stats (mean, inv_std ddof=1) reduced per block from 1024 partials
//       (deterministic tree, double accum); rowmax per strip from rmPart
//     - phase0: standardize M in place (float4); K = exp(Mstd - rowmax) kept
//       ENTIRELY IN REGISTERS (thread owns 16 rows x 8 cols = 16x halfx8)
//     - 20 Sinkhorn iters: u = r/(Kv) block-local; t = K^T u via per-block
//       partials tg[256][4096] -> owner col reduce; per-block maxdev via devArr;
//       2 tree-barriers per iter
//     - final: w = 1/(Kv); s = K^T w; P_ij = K_ij*w_i/s_j; loss = ||P-I||_F

#define NN 4096
#define DIM 1024
#define OT_ITERS 20
#define OT_EPS_F 1e-6f
#define RC (1.0f/4096.0f)
#define RPB 16   // K rows per block
#define SBT 512  // sinkhorn block threads (8 cols each)

typedef __bf16 bf16_t;
typedef _Float16 half_t;
typedef __bf16 bf16x8 __attribute__((ext_vector_type(8)));
typedef _Float16 halfx8 __attribute__((ext_vector_type(8)));
typedef float floatx4 __attribute__((ext_vector_type(4)));

typedef __attribute__((address_space(1))) void gv_t;
typedef __attribute__((address_space(3))) void lv_t;

// async global->LDS, 16B per lane; lds dst = wave-uniform base, HW adds lane*16
__device__ __forceinline__ void gld_lds16(const void* g, void* lds_uniform) {
  uint32_t loff = (uint32_t)(uintptr_t)lds_uniform;
  loff = (uint32_t)__builtin_amdgcn_readfirstlane((int)loff);
  __builtin_amdgcn_global_load_lds((gv_t*)(uintptr_t)g, (lv_t*)(uintptr_t)loff, 16, 0, 0);
}

// ---- 2-level tree grid barrier --------------------------------------------
// bar layout (uint32 words): cnt[grp] at grp*64 (grp<8, separate lines),
// root at 512, gen at 576. All zeroed by init_ws each launch.
__device__ __forceinline__ void gbar(uint32_t* bar, uint32_t g) {
  __syncthreads();  // compiler drains vmcnt before s_barrier -> stores visible
  if (threadIdx.x == 0) {
    uint32_t* cnt = bar + ((blockIdx.x >> 5) * 64);
    uint32_t* root = bar + 512;
    uint32_t* gen = bar + 576;
    if (__hip_atomic_fetch_add(cnt, 1u, __ATOMIC_RELEASE, __HIP_MEMORY_SCOPE_AGENT) == 31u) {
      __hip_atomic_store(cnt, 0u, __ATOMIC_RELAXED, __HIP_MEMORY_SCOPE_AGENT);
      if (__hip_atomic_fetch_add(root, 1u, __ATOMIC_ACQ_REL, __HIP_MEMORY_SCOPE_AGENT) == 7u) {
        __hip_atomic_store(root, 0u, __ATOMIC_RELAXED, __HIP_MEMORY_SCOPE_AGENT);
        __hip_atomic_store(gen, g, __ATOMIC_RELEASE, __HIP_MEMORY_SCOPE_AGENT);
      }
    }
    while (__hip_atomic_load(gen, __ATOMIC_RELAXED, __HIP_MEMORY_SCOPE_AGENT) < g)
      __builtin_amdgcn_s_sleep(1);
    __builtin_amdgcn_fence(__ATOMIC_ACQUIRE, "agent");
  }
  __syncthreads();
}

// ---------------- init ----------------
__global__ void init_ws(float* scal, uint32_t* bar) {
  int i = blockIdx.x * 256 + threadIdx.x;
  if (i < 8) ((uint32_t*)scal)[i] = 0u;  // [4]=lossAcc
  if (i < 640) bar[i] = 0u;              // barrier state
}

// ---------------- row normalize + bf16 cast ----------------
__global__ __launch_bounds__(256) void norm_rows(const float* __restrict__ X,
                                                 bf16_t* __restrict__ Y) {
  int tid = threadIdx.x;
  int wave = tid >> 6, lane = tid & 63;
  int row = blockIdx.x * 4 + wave;
  const float* xr = X + (size_t)row * DIM;
  float xv[16];
  float ss = 0.f;
#pragma unroll
  for (int k = 0; k < 16; k++) { xv[k] = xr[lane + 64 * k]; ss += xv[k] * xv[k]; }
#pragma unroll
  for (int off = 1; off < 64; off <<= 1) ss += __shfl_xor(ss, off, 64);
  float inv = rsqrtf(ss);  // norm ~ 32 >> 1e-12 floor, floor never binds
  bf16_t* yr = Y + (size_t)row * DIM;
#pragma unroll
  for (int k = 0; k < 16; k++) yr[lane + 64 * k] = (bf16_t)(xv[k] * inv);
}

// ---------------- GEMM: C = A @ B^T (both row-major, K-contiguous) ----------------
__global__ __launch_bounds__(256) void gemm_bt(const bf16_t* __restrict__ A,
                                               const bf16_t* __restrict__ B,
                                               float* __restrict__ C,
                                               float* __restrict__ sumArr,
                                               float* __restrict__ sqArr,
                                               float* __restrict__ rmPart) {
  __shared__ __align__(16) bf16_t As[128 * 32];
  __shared__ __align__(16) bf16_t Bs[128 * 32];
  __shared__ float sred[8];
  int tid = threadIdx.x;
  int wave = tid >> 6, lane = tid & 63;
  int quad = lane >> 4, l16 = lane & 15;
  int bm = blockIdx.y, bn = blockIdx.x;
  int waveM = wave >> 1, waveN = wave & 1;  // 2x2 waves, each 64x64
  floatx4 acc[4][4] = {};

  for (int k0 = 0; k0 < DIM; k0 += 32) {
#pragma unroll
    for (int t = 0; t < 2; t++) {
      int cbase = t * 256 + wave * 64;  // wave-uniform chunk base
      int c = cbase + lane;             // chunk: 16B = 8 bf16
      int row = c >> 2, kc = c & 3;     // tile row, k-subchunk
      gld_lds16(A + (size_t)(bm * 128 + row) * DIM + (k0 + kc * 8), (char*)As + (size_t)cbase * 16);
      gld_lds16(B + (size_t)(bn * 128 + row) * DIM + (k0 + kc * 8), (char*)Bs + (size_t)cbase * 16);
    }
    __syncthreads();  // drains vmcnt before barrier
    bf16x8 af[4], bfr[4];
#pragma unroll
    for (int mt = 0; mt < 4; mt++)
      af[mt] = *(const bf16x8*)(As + (waveM * 64 + mt * 16 + l16) * 32 + quad * 8);
#pragma unroll
    for (int nt = 0; nt < 4; nt++)
      bfr[nt] = *(const bf16x8*)(Bs + (waveN * 64 + nt * 16 + l16) * 32 + quad * 8);
#pragma unroll
    for (int mt = 0; mt < 4; mt++)
#pragma unroll
      for (int nt = 0; nt < 4; nt++)
        acc[mt][nt] = __builtin_amdgcn_mfma_f32_16x16x32_bf16(af[mt], bfr[nt], acc[mt][nt], 0, 0, 0);
    __syncthreads();
  }

  // epilogue: write C (fp32); per-block sum/sq partials; per-block row maxes.
  // C/D layout (m89-verified): col = lane&15, row = quad*4 + reg
  float lsum = 0.f, lsq = 0.f;
#pragma unroll
  for (int mt = 0; mt < 4; mt++) {
#pragma unroll
    for (int r = 0; r < 4; r++) {
      int gi = bm * 128 + waveM * 64 + mt * 16 + quad * 4 + r;
      float rmax = -3.4e38f;
#pragma unroll
      for (int nt = 0; nt < 4; nt++) {
        float vv = acc[mt][nt][r];
        int gj = bn * 128 + waveN * 64 + nt * 16 + l16;
        C[(size_t)gi * NN + gj] = vv;
        lsum += vv;
        lsq += vv * vv;
        rmax = fmaxf(rmax, vv);
      }
#pragma unroll
      for (int off = 1; off < 16; off <<= 1) rmax = fmaxf(rmax, __shfl_xor(rmax, off, 64));
      // half the rows of this 128-row tile belong to waveN==0 waves, half to
      // waveN==1; each (gi) is produced by exactly 2 waves (waveN=0/1) with
      // DIFFERENT rmax (different 64-col halves) -> combine: store per waveN
      // then max at read time. Layout: rmPart[(bn*2+waveN)*NN + gi].
      if (l16 == 0) rmPart[(size_t)(bn * 2 + waveN) * NN + gi] = rmax;
    }
  }
#pragma unroll
  for (int off = 1; off < 64; off <<= 1) {
    lsum += __shfl_xor(lsum, off, 64);
    lsq += __shfl_xor(lsq, off, 64);
  }
  if (lane == 0) { sred[wave] = lsum; sred[4 + wave] = lsq; }
  __syncthreads();
  if (tid == 0) {
    int bid = bm * 32 + bn;
    sumArr[bid] = sred[0] + sred[1] + sred[2] + sred[3];
    sqArr[bid] = sred[4] + sred[5] + sred[6] + sred[7];
  }
}

// ---------------- fused persistent Sinkhorn ----------------
// PLAIN launch: 256 blocks x 512 threads; grid == #CUs -> all co-resident.
// Block b owns K rows [16b,16b+16); thread owns cols [8*tid, 8*tid+8).
__global__ __launch_bounds__(SBT, 1) void sinkhorn_full(
    float* __restrict__ M,            // in: M_raw (GEMM out), out: standardized M
    float* __restrict__ P,            // P output (out+1, NOT 16B aligned -> scalar stores)
    float* __restrict__ scal,         // [4]=lossAcc
    const float* __restrict__ sumArr, // [1024] per-gemm-block sums
    const float* __restrict__ sqArr,  // [1024] per-gemm-block sumsq
    const float* __restrict__ rmPart, // [64][4096] per-(bn,waveN) row maxes
    float* __restrict__ t,            // [4096] colsum K^T u
    float* __restrict__ s,            // [4096] final colsum
    float* __restrict__ tg,           // [256][4096] per-block partials
    float* __restrict__ devArr,       // [256] per-block maxdev
    uint32_t* __restrict__ bar,       // tree-barrier state
    float* __restrict__ out) {        // out[0] = loss
  __shared__ float red[8 * RPB];   // 8 waves x 16 row-partials
  __shared__ float u_lds[RPB];
  __shared__ float scratch[SBT];
  __shared__ float rowmax_l[RPB];
  __shared__ double dred[16];
  __shared__ float stat_l[2];

  const int b = blockIdx.x;
  const int tid = threadIdx.x;
  const int wave = tid >> 6, lane = tid & 63;
  const int g0 = b * RPB;
  const int c0 = tid * 8;  // this thread's 8 columns
  uint32_t bg = 0;         // barrier generation (identical sequence in every block)

  // ---- stats: deterministic tree over 1024 per-block partials (double) ----
  {
    double ds = (double)sumArr[tid] + (double)sumArr[tid + 512];
    double dq = (double)sqArr[tid] + (double)sqArr[tid + 512];
#pragma unroll
    for (int off = 1; off < 64; off <<= 1) {
      ds += __shfl_xor(ds, off, 64);
      dq += __shfl_xor(dq, off, 64);
    }
    if (lane == 0) { dred[wave] = ds; dred[8 + wave] = dq; }
  }
  // ---- per-strip row maxes from rmPart: 16 rows x 64 partials ----
  {
    int row = tid >> 5, half = tid & 31;          // 16 x 32
    float rm = fmaxf(rmPart[(size_t)(half * 2) * NN + g0 + row],
                     rmPart[(size_t)(half * 2 + 1) * NN + g0 + row]);
#pragma unroll
    for (int off = 1; off < 32; off <<= 1) rm = fmaxf(rm, __shfl_xor(rm, off, 64));
    if (half == 0) rowmax_l[row] = rm;
  }
  __syncthreads();
  if (tid == 0) {
    double sum = 0.0, sumsq = 0.0;
#pragma unroll
    for (int w = 0; w < 8; w++) { sum += dred[w]; sumsq += dred[8 + w]; }
    double Nd = (double)NN * (double)NN;
    double meand = sum / Nd;
    double var = (sumsq - sum * sum / Nd) / (Nd - 1.0);  // ddof=1
    stat_l[0] = (float)meand;
    stat_l[1] = (float)(1.0 / sqrt(var));
  }
  __syncthreads();
  const float mean = stat_l[0], istd = stat_l[1];

  // ---- phase 0: standardize M strip in place (float4), K strip in registers ----
  halfx8 kreg[RPB];
#pragma unroll
  for (int i = 0; i < RPB; i++) {
    float rmax = rowmax_l[i];
    float* mrow = M + (size_t)(g0 + i) * NN + c0;
    float4 a = *(const float4*)mrow;
    float4 bb = *(const float4*)(mrow + 4);
    float4 sa, sb;
    sa.x = (a.x - mean) * istd;  sa.y = (a.y - mean) * istd;
    sa.z = (a.z - mean) * istd;  sa.w = (a.w - mean) * istd;
    sb.x = (bb.x - mean) * istd; sb.y = (bb.y - mean) * istd;
    sb.z = (bb.z - mean) * istd; sb.w = (bb.w - mean) * istd;
    *(float4*)mrow = sa;
    *(float4*)(mrow + 4) = sb;
    halfx8 kp;
    kp[0] = (half_t)__expf((a.x - rmax) * istd);
    kp[1] = (half_t)__expf((a.y - rmax) * istd);
    kp[2] = (half_t)__expf((a.z - rmax) * istd);
    kp[3] = (half_t)__expf((a.w - rmax) * istd);
    kp[4] = (half_t)__expf((bb.x - rmax) * istd);
    kp[5] = (half_t)__expf((bb.y - rmax) * istd);
    kp[6] = (half_t)__expf((bb.z - rmax) * istd);
    kp[7] = (half_t)__expf((bb.w - rmax) * istd);
    kreg[i] = kp;
  }

  float vr[8];  // v for this thread's 8 columns (register-resident)
#pragma unroll
  for (int q = 0; q < 8; q++) vr[q] = 1.0f;

  // u_i = scale / sum_j K_ij v_j for block rows; then tg[b][:] = partial K^T u
  auto matvec_phase = [&](float scale) {
    float part[RPB];
#pragma unroll
    for (int i = 0; i < RPB; i++) {
      float p = 0.f;
#pragma unroll
      for (int q = 0; q < 8; q++) p += (float)kreg[i][q] * vr[q];
      part[i] = p;
    }
#pragma unroll
    for (int off = 1; off < 64; off <<= 1)
#pragma unroll
      for (int i = 0; i < RPB; i++) part[i] += __shfl_xor(part[i], off, 64);
    if (lane == 0) {
#pragma unroll
      for (int i = 0; i < RPB; i++) red[wave * RPB + i] = part[i];
    }
    __syncthreads();
    if (tid < RPB) {
      float dsum = 0.f;
#pragma unroll
      for (int w = 0; w < 8; w++) dsum += red[w * RPB + tid];
      u_lds[tid] = scale / dsum;
    }
    __syncthreads();
    float ta[8];
#pragma unroll
    for (int q = 0; q < 8; q++) ta[q] = 0.f;
#pragma unroll
    for (int i = 0; i < RPB; i++) {
      float ui = u_lds[i];
#pragma unroll
      for (int q = 0; q < 8; q++) ta[q] += (float)kreg[i][q] * ui;
    }
    float* tgb = tg + (size_t)b * NN;
#pragma unroll
    for (int q = 0; q < 8; q++) tgb[c0 + q] = ta[q];
  };

  // deterministic fixed-order reduce of tg over 256 blocks for this block's
  // 16 owned columns; result valid for tid < 16
  auto colreduce = [&]() -> float {
    int jl = tid & 15, seg = tid >> 4;  // seg in [0,32), 8 partials each
    int j = g0 + jl;
    float acc = 0.f;
#pragma unroll
    for (int m = 0; m < 8; m++) acc += tg[(size_t)(seg * 8 + m) * NN + j];
    scratch[tid] = acc;
    __syncthreads();
    float tn = 0.f;
    if (tid < RPB) {
#pragma unroll
      for (int k = 0; k < 32; k++) tn += scratch[tid + RPB * k];
    }
    return tn;
  };

  // ---- Sinkhorn loop: u = r/(Kv); t = K^T u; maxdev; v = c/t ----
  bool frozen = false;
  for (int it = 0; it < OT_ITERS; it++) {
    if (it > 0) {
      float4 t0 = *(const float4*)(t + c0);
      float4 t1 = *(const float4*)(t + c0 + 4);
      vr[0] = RC / t0.x; vr[1] = RC / t0.y; vr[2] = RC / t0.z; vr[3] = RC / t0.w;
      vr[4] = RC / t1.x; vr[5] = RC / t1.y; vr[6] = RC / t1.z; vr[7] = RC / t1.w;
    }
    matvec_phase(RC);
    gbar(bar, ++bg);
    float tn = colreduce();
    if (tid < RPB) {
      int j = g0 + tid;
      float vj = (it == 0) ? 1.0f : (RC / t[j]);  // v used THIS iter
      float dev = fabsf(vj * tn - RC);            // beta_j - c
      t[j] = tn;
#pragma unroll
      for (int off = 1; off < RPB; off <<= 1) dev = fmaxf(dev, __shfl_xor(dev, off, 64));
      if (tid == 0) devArr[b] = dev;  // per-block store: no contended atomics
    }
    gbar(bar, ++bg);
    // block-local max over 256 per-block devs (max is exact -> deterministic)
    float x = (tid < 256) ? devArr[tid] : 0.f;
#pragma unroll
    for (int off = 1; off < 64; off <<= 1) x = fmaxf(x, __shfl_xor(x, off, 64));
    if (lane == 0 && wave < 4) scratch[300 + wave] = x;
    __syncthreads();
    float md = fmaxf(fmaxf(scratch[300], scratch[301]), fmaxf(scratch[302], scratch[303]));
    if (md <= OT_EPS_F) { frozen = true; break; }  // uniform across blocks
  }
  if (!frozen) {
#pragma unroll
    for (int q = 0; q < 8; q++) vr[q] = RC / t[c0 + q];  // commit final col-normalize v
  }

  // ---- final: w = 1/(Kv); s = K^T w; P_ij = K_ij * w_i / s_j (v cancels) ----
  matvec_phase(1.0f);  // u_lds now holds w_i
  gbar(bar, ++bg);
  float tn = colreduce();
  if (tid < RPB) s[g0 + tid] = tn;
  gbar(bar, ++bg);

  float4 s0 = *(const float4*)(s + c0);
  float4 s1 = *(const float4*)(s + c0 + 4);
  float isv[8] = {1.0f / s0.x, 1.0f / s0.y, 1.0f / s0.z, 1.0f / s0.w,
                  1.0f / s1.x, 1.0f / s1.y, 1.0f / s1.z, 1.0f / s1.w};
  float ls = 0.f;
#pragma unroll
  for (int i = 0; i < RPB; i++) {
    int gi = g0 + i;
    float wi = u_lds[i];
    float* prow = P + (size_t)gi * NN;  // unaligned base (out+1): scalar stores
#pragma unroll
    for (int q = 0; q < 8; q++) {
      float p = (float)kreg[i][q] * wi * isv[q];
      prow[c0 + q] = p;
      float d = p - ((gi == c0 + q) ? 1.0f : 0.0f);
      ls += d * d;
    }
  }
#pragma unroll
  for (int off = 1; off < 64; off <<= 1) ls += __shfl_xor(ls, off, 64);
  __syncthreads();
  if (lane == 0) red[wave] = ls;
  __syncthreads();
  if (tid == 0) {
    float tot = 0.f;
#pragma unroll
    for (int w = 0; w < 8; w++) tot += red[w];
    atomicAdd(&scal[4], tot);
  }
  gbar(bar, ++bg);
  if (b == 0 && tid == 0) out[0] = sqrtf(scal[4]);
}

// ---------------- launch ----------------
extern "C" void kernel_launch(void* const* d_in, const int* in_sizes, int n_in, void* d_out,
                              int out_size, void* d_ws, size_t ws_size, hipStream_t stream) {
  const float* ft = (const float*)d_in[0];
  const float* fs = (const float*)d_in[1];
  float* out = (float*)d_out;

  char* ws = (char*)d_ws;
  bf16_t* A = (bf16_t*)ws;                  //  8 MiB
  bf16_t* B = (bf16_t*)(ws + (8u << 20));   //  8 MiB
  float* tg = (float*)(ws + (16u << 20));   //  4 MiB: per-block col partials
  float* fbase = (float*)(ws + (24u << 20));
  float* t = fbase;                              // 4096
  float* s = fbase + 4096;                       // 4096
  float* devArr = fbase + 8192;                  // 256
  float* scal = fbase + 8448;                    // 8 ([4]=lossAcc)
  uint32_t* bar = (uint32_t*)(fbase + 8704);     // 640 words (spaced counters)
  float* sumArr = fbase + 10240;                 // 1024
  float* sqArr = fbase + 11264;                  // 1024
  float* rmPart = fbase + 16384;                 // 64*4096 (per bn x waveN row maxes)

  float* P_out = out + 1;
  float* M_out = out + 1 + (size_t)NN * NN;  // scratch for M_raw, then standardized M

  init_ws<<<3, 256, 0, stream>>>(scal, bar);
  norm_rows<<<1024, 256, 0, stream>>>(ft, A);
  norm_rows<<<1024, 256, 0, stream>>>(fs, B);
  gemm_bt<<<dim3(32, 32), 256, 0, stream>>>(A, B, M_out, sumArr, sqArr, rmPart);

  sinkhorn_full<<<256, SBT, 0, stream>>>(M_out, P_out, scal, sumArr, sqArr, rmPart, t, s, tg,
                                         devArr, bar, out);
}